// Round 4
// baseline (7268.102 us; speedup 1.0000x reference)
//
#include <hip/hip_runtime.h>
#include <cmath>

// ---------------------------------------------------------------------------
// OmniAnomaly forward, round 3: weight-stationary interval body (as round 2)
// but launched as 103 ordinary kernels -- kernel boundary = grid barrier.
// Blocks 0..127: q-GRU (t=iv), blocks 128..255: p-GRU (t=iv-2); every block
// also does flow (tf=iv-1) for 4 batch rows and recon (tr=iv-3).
// Each block's 3-gate x 16-col weight slice (~55 KB bf16) is loaded into LDS
// at launch (from L2) and used for all 16-18 k-tiles with zero barriers in
// the k-loop. No cooperative launch this round (round-2 coop launch failed
// silently: outputs were never written -- identical absmax to the empty
// stub). ws footprint kept at round-1's proven ~15.6 MB (no xbf staging).
// ---------------------------------------------------------------------------

#define B_  1024
#define T_  100
#define XD_ 38
#define H_  500
#define ZD_ 16
#define L_  3
#define NI_ 103

typedef short bf16x8 __attribute__((ext_vector_type(8)));
typedef float f32x4  __attribute__((ext_vector_type(4)));
typedef unsigned short ushort;

__device__ __forceinline__ ushort f2bf(float f) {
    union { float f; unsigned u; } v; v.f = f;
    unsigned r = (v.u + 0x7FFF + ((v.u >> 16) & 1)) >> 16;   // RNE
    return (ushort)r;
}
__device__ __forceinline__ float sigf(float x) { return 1.0f / (1.0f + __expf(-x)); }
__device__ __forceinline__ float tanh_(float x) {
    float e = __expf(2.0f * x);
    return 1.0f - 2.0f / (e + 1.0f);
}
__device__ __forceinline__ float softplus_(float x) {
    return fmaxf(x, 0.0f) + log1pf(__expf(-fabsf(x)));
}
__device__ __forceinline__ float grp16_sum(float v) {
    v += __shfl_xor(v, 1, 16);
    v += __shfl_xor(v, 2, 16);
    v += __shfl_xor(v, 4, 16);
    v += __shfl_xor(v, 8, 16);
    return v;
}

// ------------------------- weight conversion -------------------------------
// Wq [3][512][576]: k<500 = Whh_q, k in [512,550) = Wih_q, else 0.
__global__ __launch_bounds__(256) void convQ(ushort* __restrict__ dst,
                                             const float* __restrict__ Whh,
                                             const float* __restrict__ Wih)
{
    int i = blockIdx.x * 256 + threadIdx.x;
    int k = i % 576, j = (i / 576) & 511, g = i / (576 * 512);
    float v = 0.f;
    if (j < 500) {
        if (k < 500)                  v = Whh[(size_t)(g * 500 + j) * 500 + k];
        else if (k >= 512 && k < 550) v = Wih[(size_t)(g * 500 + j) * 38 + (k - 512)];
    }
    dst[i] = f2bf(v);
}
// Wp [3][512][544]: k<500 = Whh_p, k in [512,528) = Wih_p, else 0.
__global__ __launch_bounds__(256) void convP(ushort* __restrict__ dst,
                                             const float* __restrict__ Whh,
                                             const float* __restrict__ Wih)
{
    int i = blockIdx.x * 256 + threadIdx.x;
    int k = i % 544, j = (i / 544) & 511, g = i / (544 * 512);
    float v = 0.f;
    if (j < 500) {
        if (k < 500)                  v = Whh[(size_t)(g * 500 + j) * 500 + k];
        else if (k >= 512 && k < 528) v = Wih[(size_t)(g * 500 + j) * 16 + (k - 512)];
    }
    dst[i] = f2bf(v);
}

// ------------------------------- params ------------------------------------
struct OmniParams {
    const ushort *Wq, *Wp;
    const float *x;
    const float *bihq, *bhhq, *bihp, *bhhp;
    const float *Wqm, *bqm, *Wqs, *bqs, *Wpm, *bpm, *Wps, *bps;
    const float *eps, *fu, *fw, *fb;
    float *hqf0, *hqf1, *hpf0, *hpf1;
    ushort *hqb0, *hqb1, *hpb0, *hpb1;
    ushort *zb0, *zb1;
    float *ldst;
    float *o_rm, *o_rs, *o_z, *o_zm, *o_zs, *o_ld;
};

// ----------------- LDS weight slice load (once per launch) -----------------
__device__ __forceinline__ void load_weights(const OmniParams& P, bool isQ,
                                             int n0, ushort* Wlds)
{
    const int tid = threadIdx.x;
    const int NKT = isQ ? 18 : 17;
    const int KP  = isQ ? 576 : 544;
    const ushort* Wsrc = isQ ? P.Wq : P.Wp;
    int chunks = 3 * NKT * 64;             // 8-elem (16 B) chunks
    for (int c = tid; c < chunks; c += 256) {
        int e = c * 8;
        int g = e / (NKT * 512);
        int r = e - g * NKT * 512;
        int kt = r >> 9;
        int off = r & 511;
        int lnr = off >> 5, ko = off & 31;
        uint4 v = *(const uint4*)(Wsrc + (size_t)(g * 512 + n0 + lnr) * KP + kt * 32 + ko);
        *(uint4*)&Wlds[e] = v;
    }
}

// ------------------------- one pipeline interval ---------------------------
__device__ void interval_body(const OmniParams& P, int iv,
                              ushort* Wlds, float* fscratch)
{
    const int tid = threadIdx.x;
    const int bid = blockIdx.x;
    const bool isQ = bid < 128;
    const int gb = isQ ? bid : bid - 128;
    const int m0 = (gb >> 5) * 256;        // 4 m-tiles of 256 rows
    const int n0 = (gb & 31) * 16;         // 32 n-tiles of 16 cols
    const int NKT1 = 16;
    const int NKT = isQ ? 18 : 17;

    const int w  = tid >> 6;               // wave id = m-subtile
    const int ln = tid & 15;
    const int qd = (tid >> 4) & 3;
    const int r0 = bid * 4;                // flow/recon batch rows

    float*  hqf[2] = { P.hqf0, P.hqf1 };
    float*  hpf[2] = { P.hpf0, P.hpf1 };
    ushort* hqb[2] = { P.hqb0, P.hqb1 };
    ushort* hpb[2] = { P.hpb0, P.hpb1 };
    ushort* zb[2]  = { P.zb0,  P.zb1  };

    // ================= GEMM + GRU cell =================
    int t = isQ ? iv : iv - 2;
    if (t >= 0 && t < T_) {
        const int col = n0 + ln;
        const bool colOK = col < H_;
        const float* bih = isQ ? P.bihq : P.bihp;
        const float* bhh = isQ ? P.bhhq : P.bhhp;
        float bR = 0.f, bZ = 0.f, bNx = 0.f, bNh = 0.f;
        if (colOK) {
            bR  = bih[col] + bhh[col];
            bZ  = bih[H_ + col] + bhh[H_ + col];
            bNx = bih[2 * H_ + col];
            bNh = bhh[2 * H_ + col];
        }
        const int par = t & 1, pp = par ^ 1;
        const ushort* Abf   = isQ ? hqb[pp] : hpb[pp];
        const float*  AoldF = isQ ? hqf[pp] : hpf[pp];
        float*  outF = isQ ? hqf[par] : hpf[par];
        ushort* outB = isQ ? hqb[par] : hpb[par];
        const ushort* Tail = zb[par];          // p tail (z_t)
        const int first = (t == 0);
        const int kt0 = first ? NKT1 : 0;

        f32x4 accR[4], accZ[4], accNh[4], accNx[4];
        #pragma unroll
        for (int mi = 0; mi < 4; ++mi) {
            accR[mi]  = f32x4{0.f,0.f,0.f,0.f};
            accZ[mi]  = f32x4{0.f,0.f,0.f,0.f};
            accNh[mi] = f32x4{0.f,0.f,0.f,0.f};
            accNx[mi] = f32x4{0.f,0.f,0.f,0.f};
        }

        uint4 aPre[4];
        auto loadA = [&](int kt) {
            #pragma unroll
            for (int mi = 0; mi < 4; ++mi) {
                int row = m0 + w * 64 + mi * 16 + ln;
                if (kt < NKT1) {
                    aPre[mi] = *(const uint4*)(Abf + (size_t)row * 512 + kt * 32 + qd * 8);
                } else if (isQ) {
                    // inline fp32 x -> bf16 (k padded with zeros)
                    const float* xrow = P.x + ((size_t)row * T_ + t) * XD_;
                    int koff = (kt - NKT1) * 32 + qd * 8;
                    float v[8];
                    #pragma unroll
                    for (int i = 0; i < 4; ++i) {
                        int d = koff + i * 2;
                        if (d + 1 < XD_) { float2 f = *(const float2*)(xrow + d); v[2*i] = f.x; v[2*i+1] = f.y; }
                        else { v[2*i] = (d < XD_) ? xrow[d] : 0.f; v[2*i+1] = 0.f; }
                    }
                    ushort h[8];
                    #pragma unroll
                    for (int i = 0; i < 8; ++i) h[i] = f2bf(v[i]);
                    aPre[mi].x = h[0] | ((unsigned)h[1] << 16);
                    aPre[mi].y = h[2] | ((unsigned)h[3] << 16);
                    aPre[mi].z = h[4] | ((unsigned)h[5] << 16);
                    aPre[mi].w = h[6] | ((unsigned)h[7] << 16);
                } else {
                    aPre[mi] = *(const uint4*)(Tail + (size_t)row * 32 + qd * 8);
                }
            }
        };
        loadA(kt0);
        for (int kt = kt0; kt < NKT; ++kt) {
            bf16x8 af[4];
            #pragma unroll
            for (int mi = 0; mi < 4; ++mi) af[mi] = *(const bf16x8*)&aPre[mi];
            if (kt + 1 < NKT) loadA(kt + 1);

            bf16x8 bf0 = *(const bf16x8*)&Wlds[((0 * NKT + kt) << 9) + ln * 32 + qd * 8];
            bf16x8 bf1 = *(const bf16x8*)&Wlds[((1 * NKT + kt) << 9) + ln * 32 + qd * 8];
            bf16x8 bf2 = *(const bf16x8*)&Wlds[((2 * NKT + kt) << 9) + ln * 32 + qd * 8];

            if (kt < NKT1) {
                #pragma unroll
                for (int mi = 0; mi < 4; ++mi) {
                    accR[mi]  = __builtin_amdgcn_mfma_f32_16x16x32_bf16(af[mi], bf0, accR[mi], 0, 0, 0);
                    accZ[mi]  = __builtin_amdgcn_mfma_f32_16x16x32_bf16(af[mi], bf1, accZ[mi], 0, 0, 0);
                    accNh[mi] = __builtin_amdgcn_mfma_f32_16x16x32_bf16(af[mi], bf2, accNh[mi], 0, 0, 0);
                }
            } else {
                #pragma unroll
                for (int mi = 0; mi < 4; ++mi) {
                    accR[mi]  = __builtin_amdgcn_mfma_f32_16x16x32_bf16(af[mi], bf0, accR[mi], 0, 0, 0);
                    accZ[mi]  = __builtin_amdgcn_mfma_f32_16x16x32_bf16(af[mi], bf1, accZ[mi], 0, 0, 0);
                    accNx[mi] = __builtin_amdgcn_mfma_f32_16x16x32_bf16(af[mi], bf2, accNx[mi], 0, 0, 0);
                }
            }
        }

        // epilogue: GRU cell, write fp32 + bf16 h
        #pragma unroll
        for (int mi = 0; mi < 4; ++mi) {
            #pragma unroll
            for (int r = 0; r < 4; ++r) {
                int row = m0 + w * 64 + mi * 16 + qd * 4 + r;
                size_t o = (size_t)row * 512 + col;
                if (colOK) {
                    float rr = sigf(accR[mi][r] + bR);
                    float zz = sigf(accZ[mi][r] + bZ);
                    float nn = tanh_(accNx[mi][r] + bNx + rr * (accNh[mi][r] + bNh));
                    float hold = first ? 0.f : AoldF[o];
                    float hn = (1.f - zz) * nn + zz * hold;
                    outF[o] = hn;
                    outB[o] = f2bf(hn);
                } else {
                    outF[o] = 0.f;
                    outB[o] = 0;
                }
            }
        }
    }

    // ================= flow (q heads + planar flows) =================
    int tf = iv - 1;
    if (tf >= 0 && tf < T_) {
        int frow = tid >> 6, rem = tid & 63, fc = rem >> 1, half = rem & 1;
        int fb_ = r0 + frow;
        const float* hrow = hqf[tf & 1] + (size_t)fb_ * 512;
        const float* wrow = (fc < 16) ? (P.Wqm + fc * 516) : (P.Wqs + (fc - 16) * 516);
        int k0 = half ? 248 : 0, k1 = half ? 500 : 248;
        float s = 0.f;
        for (int k = k0; k < k1; k += 4) {
            float4 h4 = *(const float4*)(hrow + k);
            float4 w4 = *(const float4*)(wrow + k);
            s += h4.x * w4.x + h4.y * w4.y + h4.z * w4.z + h4.w * w4.w;
        }
        if (half && tf > 0) {
            const float* zp = P.o_z + ((size_t)fb_ * T_ + tf - 1) * ZD_;
            #pragma unroll
            for (int i = 0; i < ZD_; ++i) s += zp[i] * wrow[500 + i];
        }
        s += __shfl_xor(s, 1);
        if (!half) fscratch[frow * 32 + fc] = s;
        __syncthreads();
        if (tid < 64) {
            int rr = tid >> 4, zd = tid & 15;
            int bb = r0 + rr;
            float mu = fscratch[rr * 32 + zd] + P.bqm[zd];
            float sq = fscratch[rr * 32 + 16 + zd] + P.bqs[zd];
            float sd = softplus_(sq) + 1e-4f;
            size_t oi = ((size_t)bb * T_ + tf) * ZD_ + zd;
            float zk = mu + P.eps[oi] * sd;
            P.o_zm[oi] = mu;
            P.o_zs[oi] = sd;
            float lsum = 0.f;
            #pragma unroll
            for (int k = 0; k < L_; ++k) {
                float w_ = P.fw[k * ZD_ + zd], u_ = P.fu[k * ZD_ + zd];
                float wu = grp16_sum(w_ * u_);
                float ww = grp16_sum(w_ * w_);
                float uh = u_ + (-1.f + softplus_(wu) - wu) * w_ / (ww + 1e-6f);
                float hh = tanh_(grp16_sum(zk * w_) + P.fb[k]);
                zk = fmaf(uh, hh, zk);
                float det = 1.f + grp16_sum((1.f - hh * hh) * w_ * uh);
                lsum += logf(fabsf(det) + 1e-6f);
            }
            P.o_z[oi] = zk;
            ushort* zbw = zb[tf & 1];
            zbw[bb * 32 + zd] = f2bf(zk);
            zbw[bb * 32 + 16 + zd] = 0;
            if (zd == 0) {
                float tot = (tf == 0 ? 0.f : P.ldst[bb]) + lsum;
                P.ldst[bb] = tot;
                if (tf == T_ - 1) P.o_ld[bb] = tot;
            }
        }
    }

    // ================= recon heads =================
    int tr = iv - 3;
    if (tr >= 0 && tr < T_) {
        const float* hpF = hpf[tr & 1];
        #pragma unroll
        for (int j = 0; j < 2; ++j) {
            int idx = j * 256 + tid;
            if (idx < 4 * 2 * XD_) {
                int row = idx / (2 * XD_), c = idx - row * (2 * XD_);
                int bb = r0 + row;
                bool isStd = c >= XD_;
                int cc = isStd ? c - XD_ : c;
                const float* hrow = hpF + (size_t)bb * 512;
                const float* wrow = (isStd ? P.Wps : P.Wpm) + cc * H_;
                float s = isStd ? P.bps[cc] : P.bpm[cc];
                for (int k = 0; k < H_; k += 4) {
                    float4 h4 = *(const float4*)(hrow + k);
                    float4 w4 = *(const float4*)(wrow + k);
                    s += h4.x * w4.x + h4.y * w4.y + h4.z * w4.z + h4.w * w4.w;
                }
                size_t oi = ((size_t)bb * T_ + tr) * XD_ + cc;
                if (isStd) P.o_rs[oi] = softplus_(s) + 1e-4f;
                else       P.o_rm[oi] = s;
            }
        }
    }
}

// ------------------------- one-interval kernel -----------------------------
__global__ __launch_bounds__(256, 1) void omni_step(OmniParams P, int iv)
{
    __shared__ __align__(16) ushort Wlds[3 * 18 * 512];   // 55,296 B
    __shared__ float fscratch[128];

    const int bid = blockIdx.x;
    const bool isQ = bid < 128;
    const int gb = isQ ? bid : bid - 128;
    const int n0 = (gb & 31) * 16;
    int t = isQ ? iv : iv - 2;
    if (t >= 0 && t < T_) load_weights(P, isQ, n0, Wlds);
    __syncthreads();
    interval_body(P, iv, Wlds, fscratch);
}

// ---------------------------------------------------------------------------
extern "C" void kernel_launch(void* const* d_in, const int* in_sizes, int n_in,
                              void* d_out, int out_size, void* d_ws, size_t ws_size,
                              hipStream_t stream)
{
    (void)in_sizes; (void)n_in; (void)out_size; (void)ws_size;
    const float* x     = (const float*)d_in[0];
    const float* eps   = (const float*)d_in[1];
    const float* Wih_q = (const float*)d_in[2];
    const float* Whh_q = (const float*)d_in[3];
    const float* bih_q = (const float*)d_in[4];
    const float* bhh_q = (const float*)d_in[5];
    const float* Wqm   = (const float*)d_in[6];
    const float* bqm   = (const float*)d_in[7];
    const float* Wqs   = (const float*)d_in[8];
    const float* bqs   = (const float*)d_in[9];
    const float* Wih_p = (const float*)d_in[10];
    const float* Whh_p = (const float*)d_in[11];
    const float* bih_p = (const float*)d_in[12];
    const float* bhh_p = (const float*)d_in[13];
    const float* Wpm   = (const float*)d_in[14];
    const float* bpm   = (const float*)d_in[15];
    const float* Wps   = (const float*)d_in[16];
    const float* bps   = (const float*)d_in[17];
    const float* fu    = (const float*)d_in[18];
    const float* fw    = (const float*)d_in[19];
    const float* fb    = (const float*)d_in[20];

    float* out  = (float*)d_out;
    float* o_rm = out;
    float* o_rs = out + 3891200;
    float* o_z  = out + 7782400;
    float* o_zm = out + 9420800;
    float* o_zs = out + 11059200;
    float* o_ld = out + 12697600;

    // workspace carve (256 B aligned), ~15.6 MB total
    char* p = (char*)d_ws;
    auto alloc = [&](size_t bytes) { void* r = p; p += (bytes + 255) & ~(size_t)255; return r; };
    const size_t HS = (size_t)B_ * 512;
    float*  hqf0 = (float*)alloc(HS * 4);
    float*  hqf1 = (float*)alloc(HS * 4);
    float*  hpf0 = (float*)alloc(HS * 4);
    float*  hpf1 = (float*)alloc(HS * 4);
    ushort* hqb0 = (ushort*)alloc(HS * 2);
    ushort* hqb1 = (ushort*)alloc(HS * 2);
    ushort* hpb0 = (ushort*)alloc(HS * 2);
    ushort* hpb1 = (ushort*)alloc(HS * 2);
    ushort* zb0  = (ushort*)alloc((size_t)B_ * 32 * 2);
    ushort* zb1  = (ushort*)alloc((size_t)B_ * 32 * 2);
    float*  ldst = (float*)alloc((size_t)B_ * 4);
    ushort* WqB  = (ushort*)alloc((size_t)3 * 512 * 576 * 2);
    ushort* WpB  = (ushort*)alloc((size_t)3 * 512 * 544 * 2);

    convQ<<<3456, 256, 0, stream>>>(WqB, Whh_q, Wih_q);
    convP<<<3264, 256, 0, stream>>>(WpB, Whh_p, Wih_p);

    OmniParams P;
    P.Wq = WqB; P.Wp = WpB; P.x = x;
    P.bihq = bih_q; P.bhhq = bhh_q; P.bihp = bih_p; P.bhhp = bhh_p;
    P.Wqm = Wqm; P.bqm = bqm; P.Wqs = Wqs; P.bqs = bqs;
    P.Wpm = Wpm; P.bpm = bpm; P.Wps = Wps; P.bps = bps;
    P.eps = eps; P.fu = fu; P.fw = fw; P.fb = fb;
    P.hqf0 = hqf0; P.hqf1 = hqf1; P.hpf0 = hpf0; P.hpf1 = hpf1;
    P.hqb0 = hqb0; P.hqb1 = hqb1; P.hpb0 = hpb0; P.hpb1 = hpb1;
    P.zb0 = zb0; P.zb1 = zb1; P.ldst = ldst;
    P.o_rm = o_rm; P.o_rs = o_rs; P.o_z = o_z; P.o_zm = o_zm;
    P.o_zs = o_zs; P.o_ld = o_ld;

    for (int iv = 0; iv < NI_; ++iv)
        omni_step<<<256, 256, 0, stream>>>(P, iv);
}

// Round 5
// 6246.171 us; speedup vs baseline: 1.1636x; 1.1636x over previous
//
#include <hip/hip_runtime.h>
#include <cmath>

// ---------------------------------------------------------------------------
// OmniAnomaly forward, round 4: round-3 structure (103 interval kernels,
// weight-stationary LDS slices, zero k-loop barriers) with the fp32 h-state
// mirror REMOVED. h lives only as bf16 [B,512]; GRU carry, flow heads and
// recon heads all read bf16 h (fp32 weights, fp32 accumulate). This cuts
// per-interval L2-miss traffic from ~29 MB to ~5 MB (round-3 counters:
// FETCH 18.5 MB + WRITE 10.8 MB at 400 GB/s = the whole 75 us/dispatch).
// ---------------------------------------------------------------------------

#define B_  1024
#define T_  100
#define XD_ 38
#define H_  500
#define ZD_ 16
#define L_  3
#define NI_ 103

typedef short bf16x8 __attribute__((ext_vector_type(8)));
typedef float f32x4  __attribute__((ext_vector_type(4)));
typedef unsigned short ushort;

__device__ __forceinline__ ushort f2bf(float f) {
    union { float f; unsigned u; } v; v.f = f;
    unsigned r = (v.u + 0x7FFF + ((v.u >> 16) & 1)) >> 16;   // RNE
    return (ushort)r;
}
__device__ __forceinline__ float bflo(unsigned p) {          // low bf16 -> f32
    union { unsigned u; float f; } v; v.u = p << 16; return v.f;
}
__device__ __forceinline__ float bfhi(unsigned p) {          // high bf16 -> f32
    union { unsigned u; float f; } v; v.u = p & 0xffff0000u; return v.f;
}
__device__ __forceinline__ float sigf(float x) { return 1.0f / (1.0f + __expf(-x)); }
__device__ __forceinline__ float tanh_(float x) {
    float e = __expf(2.0f * x);
    return 1.0f - 2.0f / (e + 1.0f);
}
__device__ __forceinline__ float softplus_(float x) {
    return fmaxf(x, 0.0f) + log1pf(__expf(-fabsf(x)));
}
__device__ __forceinline__ float grp16_sum(float v) {
    v += __shfl_xor(v, 1, 16);
    v += __shfl_xor(v, 2, 16);
    v += __shfl_xor(v, 4, 16);
    v += __shfl_xor(v, 8, 16);
    return v;
}

// ------------------------- weight conversion -------------------------------
// Wq [3][512][576]: k<500 = Whh_q, k in [512,550) = Wih_q, else 0.
__global__ __launch_bounds__(256) void convQ(ushort* __restrict__ dst,
                                             const float* __restrict__ Whh,
                                             const float* __restrict__ Wih)
{
    int i = blockIdx.x * 256 + threadIdx.x;
    int k = i % 576, j = (i / 576) & 511, g = i / (576 * 512);
    float v = 0.f;
    if (j < 500) {
        if (k < 500)                  v = Whh[(size_t)(g * 500 + j) * 500 + k];
        else if (k >= 512 && k < 550) v = Wih[(size_t)(g * 500 + j) * 38 + (k - 512)];
    }
    dst[i] = f2bf(v);
}
// Wp [3][512][544]: k<500 = Whh_p, k in [512,528) = Wih_p, else 0.
__global__ __launch_bounds__(256) void convP(ushort* __restrict__ dst,
                                             const float* __restrict__ Whh,
                                             const float* __restrict__ Wih)
{
    int i = blockIdx.x * 256 + threadIdx.x;
    int k = i % 544, j = (i / 544) & 511, g = i / (544 * 512);
    float v = 0.f;
    if (j < 500) {
        if (k < 500)                  v = Whh[(size_t)(g * 500 + j) * 500 + k];
        else if (k >= 512 && k < 528) v = Wih[(size_t)(g * 500 + j) * 16 + (k - 512)];
    }
    dst[i] = f2bf(v);
}

// ------------------------------- params ------------------------------------
struct OmniParams {
    const ushort *Wq, *Wp;
    const float *x;
    const float *bihq, *bhhq, *bihp, *bhhp;
    const float *Wqm, *bqm, *Wqs, *bqs, *Wpm, *bpm, *Wps, *bps;
    const float *eps, *fu, *fw, *fb;
    ushort *hqb0, *hqb1, *hpb0, *hpb1;
    ushort *zb0, *zb1;
    float *ldst;
    float *o_rm, *o_rs, *o_z, *o_zm, *o_zs, *o_ld;
};

// ----------------- LDS weight slice load (once per launch) -----------------
__device__ __forceinline__ void load_weights(const OmniParams& P, bool isQ,
                                             int n0, ushort* Wlds)
{
    const int tid = threadIdx.x;
    const int NKT = isQ ? 18 : 17;
    const int KP  = isQ ? 576 : 544;
    const ushort* Wsrc = isQ ? P.Wq : P.Wp;
    int chunks = 3 * NKT * 64;             // 8-elem (16 B) chunks
    for (int c = tid; c < chunks; c += 256) {
        int e = c * 8;
        int g = e / (NKT * 512);
        int r = e - g * NKT * 512;
        int kt = r >> 9;
        int off = r & 511;
        int lnr = off >> 5, ko = off & 31;
        uint4 v = *(const uint4*)(Wsrc + (size_t)(g * 512 + n0 + lnr) * KP + kt * 32 + ko);
        *(uint4*)&Wlds[e] = v;
    }
}

// bf16 row-dot-fp32-weights helper: sum over [k0,k1) (k1-k0 multiple of 8)
__device__ __forceinline__ float bfdot(const ushort* hrow, const float* wrow,
                                       int k0, int k1)
{
    float s = 0.f;
    for (int k = k0; k + 8 <= k1; k += 8) {
        uint4 hv = *(const uint4*)(hrow + k);
        float4 w0 = *(const float4*)(wrow + k);
        float4 w1 = *(const float4*)(wrow + k + 4);
        s += bflo(hv.x) * w0.x + bfhi(hv.x) * w0.y
           + bflo(hv.y) * w0.z + bfhi(hv.y) * w0.w
           + bflo(hv.z) * w1.x + bfhi(hv.z) * w1.y
           + bflo(hv.w) * w1.z + bfhi(hv.w) * w1.w;
    }
    return s;
}

// ------------------------- one pipeline interval ---------------------------
__device__ void interval_body(const OmniParams& P, int iv,
                              ushort* Wlds, float* fscratch)
{
    const int tid = threadIdx.x;
    const int bid = blockIdx.x;
    const bool isQ = bid < 128;
    const int gb = isQ ? bid : bid - 128;
    const int m0 = (gb >> 5) * 256;        // 4 m-tiles of 256 rows
    const int n0 = (gb & 31) * 16;         // 32 n-tiles of 16 cols
    const int NKT1 = 16;
    const int NKT = isQ ? 18 : 17;

    const int w  = tid >> 6;               // wave id = m-subtile
    const int ln = tid & 15;
    const int qd = (tid >> 4) & 3;
    const int r0 = bid * 4;                // flow/recon batch rows

    ushort* hqb[2] = { P.hqb0, P.hqb1 };
    ushort* hpb[2] = { P.hpb0, P.hpb1 };
    ushort* zb[2]  = { P.zb0,  P.zb1  };

    // ================= GEMM + GRU cell =================
    int t = isQ ? iv : iv - 2;
    if (t >= 0 && t < T_) {
        const int col = n0 + ln;
        const bool colOK = col < H_;
        const float* bih = isQ ? P.bihq : P.bihp;
        const float* bhh = isQ ? P.bhhq : P.bhhp;
        float bR = 0.f, bZ = 0.f, bNx = 0.f, bNh = 0.f;
        if (colOK) {
            bR  = bih[col] + bhh[col];
            bZ  = bih[H_ + col] + bhh[H_ + col];
            bNx = bih[2 * H_ + col];
            bNh = bhh[2 * H_ + col];
        }
        const int par = t & 1, pp = par ^ 1;
        const ushort* Abf = isQ ? hqb[pp] : hpb[pp];
        ushort* outB = isQ ? hqb[par] : hpb[par];
        const ushort* Tail = zb[par];          // p tail (z_t)
        const int first = (t == 0);
        const int kt0 = first ? NKT1 : 0;

        f32x4 accR[4], accZ[4], accNh[4], accNx[4];
        #pragma unroll
        for (int mi = 0; mi < 4; ++mi) {
            accR[mi]  = f32x4{0.f,0.f,0.f,0.f};
            accZ[mi]  = f32x4{0.f,0.f,0.f,0.f};
            accNh[mi] = f32x4{0.f,0.f,0.f,0.f};
            accNx[mi] = f32x4{0.f,0.f,0.f,0.f};
        }

        uint4 aPre[4];
        auto loadA = [&](int kt) {
            #pragma unroll
            for (int mi = 0; mi < 4; ++mi) {
                int row = m0 + w * 64 + mi * 16 + ln;
                if (kt < NKT1) {
                    aPre[mi] = *(const uint4*)(Abf + (size_t)row * 512 + kt * 32 + qd * 8);
                } else if (isQ) {
                    // inline fp32 x -> bf16 (k padded with zeros)
                    const float* xrow = P.x + ((size_t)row * T_ + t) * XD_;
                    int koff = (kt - NKT1) * 32 + qd * 8;
                    float v[8];
                    #pragma unroll
                    for (int i = 0; i < 4; ++i) {
                        int d = koff + i * 2;
                        if (d + 1 < XD_) { float2 f = *(const float2*)(xrow + d); v[2*i] = f.x; v[2*i+1] = f.y; }
                        else { v[2*i] = (d < XD_) ? xrow[d] : 0.f; v[2*i+1] = 0.f; }
                    }
                    ushort h[8];
                    #pragma unroll
                    for (int i = 0; i < 8; ++i) h[i] = f2bf(v[i]);
                    aPre[mi].x = h[0] | ((unsigned)h[1] << 16);
                    aPre[mi].y = h[2] | ((unsigned)h[3] << 16);
                    aPre[mi].z = h[4] | ((unsigned)h[5] << 16);
                    aPre[mi].w = h[6] | ((unsigned)h[7] << 16);
                } else {
                    aPre[mi] = *(const uint4*)(Tail + (size_t)row * 32 + qd * 8);
                }
            }
        };
        loadA(kt0);
        for (int kt = kt0; kt < NKT; ++kt) {
            bf16x8 af[4];
            #pragma unroll
            for (int mi = 0; mi < 4; ++mi) af[mi] = *(const bf16x8*)&aPre[mi];
            if (kt + 1 < NKT) loadA(kt + 1);

            bf16x8 bf0 = *(const bf16x8*)&Wlds[((0 * NKT + kt) << 9) + ln * 32 + qd * 8];
            bf16x8 bf1 = *(const bf16x8*)&Wlds[((1 * NKT + kt) << 9) + ln * 32 + qd * 8];
            bf16x8 bf2 = *(const bf16x8*)&Wlds[((2 * NKT + kt) << 9) + ln * 32 + qd * 8];

            if (kt < NKT1) {
                #pragma unroll
                for (int mi = 0; mi < 4; ++mi) {
                    accR[mi]  = __builtin_amdgcn_mfma_f32_16x16x32_bf16(af[mi], bf0, accR[mi], 0, 0, 0);
                    accZ[mi]  = __builtin_amdgcn_mfma_f32_16x16x32_bf16(af[mi], bf1, accZ[mi], 0, 0, 0);
                    accNh[mi] = __builtin_amdgcn_mfma_f32_16x16x32_bf16(af[mi], bf2, accNh[mi], 0, 0, 0);
                }
            } else {
                #pragma unroll
                for (int mi = 0; mi < 4; ++mi) {
                    accR[mi]  = __builtin_amdgcn_mfma_f32_16x16x32_bf16(af[mi], bf0, accR[mi], 0, 0, 0);
                    accZ[mi]  = __builtin_amdgcn_mfma_f32_16x16x32_bf16(af[mi], bf1, accZ[mi], 0, 0, 0);
                    accNx[mi] = __builtin_amdgcn_mfma_f32_16x16x32_bf16(af[mi], bf2, accNx[mi], 0, 0, 0);
                }
            }
        }

        // epilogue: GRU cell, write bf16 h only (carry read from bf16 too)
        #pragma unroll
        for (int mi = 0; mi < 4; ++mi) {
            #pragma unroll
            for (int r = 0; r < 4; ++r) {
                int row = m0 + w * 64 + mi * 16 + qd * 4 + r;
                size_t o = (size_t)row * 512 + col;
                if (colOK) {
                    float rr = sigf(accR[mi][r] + bR);
                    float zz = sigf(accZ[mi][r] + bZ);
                    float nn = tanh_(accNx[mi][r] + bNx + rr * (accNh[mi][r] + bNh));
                    float hold = first ? 0.f : bflo((unsigned)Abf[o]);
                    float hn = (1.f - zz) * nn + zz * hold;
                    outB[o] = f2bf(hn);
                } else {
                    outB[o] = 0;
                }
            }
        }
    }

    // ================= flow (q heads + planar flows) =================
    int tf = iv - 1;
    if (tf >= 0 && tf < T_) {
        int frow = tid >> 6, rem = tid & 63, fc = rem >> 1, half = rem & 1;
        int fb_ = r0 + frow;
        const ushort* hrow = hqb[tf & 1] + (size_t)fb_ * 512;
        const float* wrow = (fc < 16) ? (P.Wqm + fc * 516) : (P.Wqs + (fc - 16) * 516);
        float s;
        if (!half) {
            s = bfdot(hrow, wrow, 0, 256);
        } else {
            s = bfdot(hrow, wrow, 256, 496);
            // tail k = 496..499
            uint2 hv = *(const uint2*)(hrow + 496);
            float4 w0 = *(const float4*)(wrow + 496);
            s += bflo(hv.x) * w0.x + bfhi(hv.x) * w0.y
               + bflo(hv.y) * w0.z + bfhi(hv.y) * w0.w;
            if (tf > 0) {
                const float* zp = P.o_z + ((size_t)fb_ * T_ + tf - 1) * ZD_;
                #pragma unroll
                for (int i = 0; i < ZD_; ++i) s += zp[i] * wrow[500 + i];
            }
        }
        s += __shfl_xor(s, 1);
        if (!half) fscratch[frow * 32 + fc] = s;
        __syncthreads();
        if (tid < 64) {
            int rr = tid >> 4, zd = tid & 15;
            int bb = r0 + rr;
            float mu = fscratch[rr * 32 + zd] + P.bqm[zd];
            float sq = fscratch[rr * 32 + 16 + zd] + P.bqs[zd];
            float sd = softplus_(sq) + 1e-4f;
            size_t oi = ((size_t)bb * T_ + tf) * ZD_ + zd;
            float zk = mu + P.eps[oi] * sd;
            P.o_zm[oi] = mu;
            P.o_zs[oi] = sd;
            float lsum = 0.f;
            #pragma unroll
            for (int k = 0; k < L_; ++k) {
                float w_ = P.fw[k * ZD_ + zd], u_ = P.fu[k * ZD_ + zd];
                float wu = grp16_sum(w_ * u_);
                float ww = grp16_sum(w_ * w_);
                float uh = u_ + (-1.f + softplus_(wu) - wu) * w_ / (ww + 1e-6f);
                float hh = tanh_(grp16_sum(zk * w_) + P.fb[k]);
                zk = fmaf(uh, hh, zk);
                float det = 1.f + grp16_sum((1.f - hh * hh) * w_ * uh);
                lsum += logf(fabsf(det) + 1e-6f);
            }
            P.o_z[oi] = zk;
            ushort* zbw = zb[tf & 1];
            zbw[bb * 32 + zd] = f2bf(zk);
            zbw[bb * 32 + 16 + zd] = 0;
            if (zd == 0) {
                float tot = (tf == 0 ? 0.f : P.ldst[bb]) + lsum;
                P.ldst[bb] = tot;
                if (tf == T_ - 1) P.o_ld[bb] = tot;
            }
        }
    }

    // ================= recon heads =================
    int tr = iv - 3;
    if (tr >= 0 && tr < T_) {
        const ushort* hpB = hpb[tr & 1];
        #pragma unroll
        for (int j = 0; j < 2; ++j) {
            int idx = j * 256 + tid;
            if (idx < 4 * 2 * XD_) {
                int row = idx / (2 * XD_), c = idx - row * (2 * XD_);
                int bb = r0 + row;
                bool isStd = c >= XD_;
                int cc = isStd ? c - XD_ : c;
                const ushort* hrow = hpB + (size_t)bb * 512;
                const float* wrow = (isStd ? P.Wps : P.Wpm) + cc * H_;
                float s = (isStd ? P.bps[cc] : P.bpm[cc]) + bfdot(hrow, wrow, 0, 496);
                // tail k = 496..499
                uint2 hv = *(const uint2*)(hrow + 496);
                float4 w0 = *(const float4*)(wrow + 496);
                s += bflo(hv.x) * w0.x + bfhi(hv.x) * w0.y
                   + bflo(hv.y) * w0.z + bfhi(hv.y) * w0.w;
                size_t oi = ((size_t)bb * T_ + tr) * XD_ + cc;
                if (isStd) P.o_rs[oi] = softplus_(s) + 1e-4f;
                else       P.o_rm[oi] = s;
            }
        }
    }
}

// ------------------------- one-interval kernel -----------------------------
__global__ __launch_bounds__(256, 1) void omni_step(OmniParams P, int iv)
{
    __shared__ __align__(16) ushort Wlds[3 * 18 * 512];   // 55,296 B
    __shared__ float fscratch[128];

    const int bid = blockIdx.x;
    const bool isQ = bid < 128;
    const int gb = isQ ? bid : bid - 128;
    const int n0 = (gb & 31) * 16;
    int t = isQ ? iv : iv - 2;
    if (t >= 0 && t < T_) load_weights(P, isQ, n0, Wlds);
    __syncthreads();
    interval_body(P, iv, Wlds, fscratch);
}

// ---------------------------------------------------------------------------
extern "C" void kernel_launch(void* const* d_in, const int* in_sizes, int n_in,
                              void* d_out, int out_size, void* d_ws, size_t ws_size,
                              hipStream_t stream)
{
    (void)in_sizes; (void)n_in; (void)out_size; (void)ws_size;
    const float* x     = (const float*)d_in[0];
    const float* eps   = (const float*)d_in[1];
    const float* Wih_q = (const float*)d_in[2];
    const float* Whh_q = (const float*)d_in[3];
    const float* bih_q = (const float*)d_in[4];
    const float* bhh_q = (const float*)d_in[5];
    const float* Wqm   = (const float*)d_in[6];
    const float* bqm   = (const float*)d_in[7];
    const float* Wqs   = (const float*)d_in[8];
    const float* bqs   = (const float*)d_in[9];
    const float* Wih_p = (const float*)d_in[10];
    const float* Whh_p = (const float*)d_in[11];
    const float* bih_p = (const float*)d_in[12];
    const float* bhh_p = (const float*)d_in[13];
    const float* Wpm   = (const float*)d_in[14];
    const float* bpm   = (const float*)d_in[15];
    const float* Wps   = (const float*)d_in[16];
    const float* bps   = (const float*)d_in[17];
    const float* fu    = (const float*)d_in[18];
    const float* fw    = (const float*)d_in[19];
    const float* fb    = (const float*)d_in[20];

    float* out  = (float*)d_out;
    float* o_rm = out;
    float* o_rs = out + 3891200;
    float* o_z  = out + 7782400;
    float* o_zm = out + 9420800;
    float* o_zs = out + 11059200;
    float* o_ld = out + 12697600;

    // workspace carve (256 B aligned), ~7.8 MB total
    char* p = (char*)d_ws;
    auto alloc = [&](size_t bytes) { void* r = p; p += (bytes + 255) & ~(size_t)255; return r; };
    const size_t HS = (size_t)B_ * 512;
    ushort* hqb0 = (ushort*)alloc(HS * 2);
    ushort* hqb1 = (ushort*)alloc(HS * 2);
    ushort* hpb0 = (ushort*)alloc(HS * 2);
    ushort* hpb1 = (ushort*)alloc(HS * 2);
    ushort* zb0  = (ushort*)alloc((size_t)B_ * 32 * 2);
    ushort* zb1  = (ushort*)alloc((size_t)B_ * 32 * 2);
    float*  ldst = (float*)alloc((size_t)B_ * 4);
    ushort* WqB  = (ushort*)alloc((size_t)3 * 512 * 576 * 2);
    ushort* WpB  = (ushort*)alloc((size_t)3 * 512 * 544 * 2);

    convQ<<<3456, 256, 0, stream>>>(WqB, Whh_q, Wih_q);
    convP<<<3264, 256, 0, stream>>>(WpB, Whh_p, Wih_p);

    OmniParams P;
    P.Wq = WqB; P.Wp = WpB; P.x = x;
    P.bihq = bih_q; P.bhhq = bhh_q; P.bihp = bih_p; P.bhhp = bhh_p;
    P.Wqm = Wqm; P.bqm = bqm; P.Wqs = Wqs; P.bqs = bqs;
    P.Wpm = Wpm; P.bpm = bpm; P.Wps = Wps; P.bps = bps;
    P.eps = eps; P.fu = fu; P.fw = fw; P.fb = fb;
    P.hqb0 = hqb0; P.hqb1 = hqb1; P.hpb0 = hpb0; P.hpb1 = hpb1;
    P.zb0 = zb0; P.zb1 = zb1; P.ldst = ldst;
    P.o_rm = o_rm; P.o_rs = o_rs; P.o_z = o_z; P.o_zm = o_zm;
    P.o_zs = o_zs; P.o_ld = o_ld;

    for (int iv = 0; iv < NI_; ++iv)
        omni_step<<<256, 256, 0, stream>>>(P, iv);
}